// Round 10
// baseline (506.718 us; speedup 1.0000x reference)
//
#include <hip/hip_runtime.h>
#include <hip/hip_fp16.h>

// ---------------------------------------------------------------------------
// GATNet forward: 3x (GATConv -> ReLU -> BN) -> mean-pool -> MLP(128->64->1)
// N=100000, E=1.6M (+N self loops), HID=128, H=4, D=32, G=128.
// R21: dual-node aggregate waves. Aggregate is latency-bound (VALU 52%, HBM
// 36-47%, nothing saturated; wave cap reached) -> add ILP: lanes 0-31 take
// node n0, lanes 32-63 take n1 (both deg<=32 ~99.96% of pairs; mean deg 17).
// Wave count halves; every vector inst carries 2 independent chains.
// Fallbacks: full-wave path (deg<=64, sequential per node), 3-pass (deg>64).
// Kept from R20: fused front-end, scan-free bucket CSR, GEMM v5, POOL fusion.
// ---------------------------------------------------------------------------

typedef __bf16 bf16x8 __attribute__((ext_vector_type(8)));
typedef float  f32x4  __attribute__((ext_vector_type(4)));
typedef unsigned int u32x4 __attribute__((ext_vector_type(4)));

#define WLSZ 36864  // per-layer fragment-linear W: 18 tiles * 4 ks * 64 lanes * 8
#define MAXBKT 800  // >= ceil(Nn/128); Nn=100000 -> 782
#define BCAP   4096 // bucket capacity; mean 2176, max ~2400

// fragment-linear offset for W buffer (see R14 notes).
__device__ __forceinline__ int foff(int l, int d, int n, int k) {
    int ct = n >> 4, li = n & 15;
    int ks = k >> 5, bq = (k >> 3) & 3, j = k & 7;
    return l * WLSZ + (((ks * 18) + d * 9 + ct) * 64 + (bq << 4) + li) * 8 + j;
}

// Fused front-end. Blocks [0, nBB): edge bucketing (+ gsum zero).
// Blocks [nBB, nBB+192): param prep. Block nBB+192: gcnt binary search.
__global__ __launch_bounds__(256)
void k_front(const int* __restrict__ ei, unsigned int* __restrict__ bkt,
             int* __restrict__ bcnt, float* __restrict__ gsum,
             int* __restrict__ gcnt, const int* __restrict__ batch,
             const float* __restrict__ gamma, const float* __restrict__ beta,
             const float* __restrict__ mean, const float* __restrict__ var,
             float* __restrict__ bn_mul, float* __restrict__ bn_add,
             const float* __restrict__ W, const float* __restrict__ asrc,
             const float* __restrict__ adst, __bf16* __restrict__ WF,
             int Ne, int Nn, int nbkt, int Gg, int nBB) {
    __shared__ int lcnt[MAXBKT];
    __shared__ int lbase[MAXBKT];
    int bb = blockIdx.x;
    int tid = threadIdx.x;

    if (bb < nBB) {
        int gid = bb * 256 + tid;
        if (gid < Gg * 128) gsum[gid] = 0.f;
        for (int i = tid; i < nbkt; i += 256) lcnt[i] = 0;
        __syncthreads();
        int chunk0 = bb * 2048;
        int nnz = Ne + Nn;
        for (int i = 0; i < 8; ++i) {
            int e = chunk0 + i * 256 + tid;
            if (e < nnz) {
                int d = (e < Ne) ? ei[Ne + e] : (e - Ne);
                atomicAdd(&lcnt[d >> 7], 1);
            }
        }
        __syncthreads();
        for (int b = tid; b < nbkt; b += 256) {
            int c = lcnt[b];
            lbase[b] = (c > 0) ? atomicAdd(&bcnt[b], c) : 0;
            lcnt[b] = 0;
        }
        __syncthreads();
        for (int i = 0; i < 8; ++i) {
            int e = chunk0 + i * 256 + tid;
            if (e < nnz) {
                int s, d;
                if (e < Ne) { s = ei[e]; d = ei[Ne + e]; }
                else        { s = e - Ne; d = e - Ne; }
                int b = d >> 7;
                int r = atomicAdd(&lcnt[b], 1);
                bkt[(long)b * BCAP + lbase[b] + r] = ((unsigned)s << 7) | (unsigned)(d & 127);
            }
        }
    } else if (bb < nBB + 192) {
        int gid = (bb - nBB) * 256 + tid;
        if (gid < 384) {
            float sc = gamma[gid] / sqrtf(var[gid] + 1e-5f);
            bn_mul[gid] = sc;
            bn_add[gid] = beta[gid] - mean[gid] * sc;
        }
        if (gid < 3 * 128 * 128) {
            int l = gid >> 14;
            int k = (gid >> 7) & 127;
            int n = gid & 127;
            float f = W[gid];
            __bf16 h = (__bf16)f;
            WF[foff(l, 0, n, k)] = h;
            WF[foff(l, 1, n, k)] = (__bf16)(f - (float)h);
        }
        if (gid < 3 * 128 * 8) {            // wa projections -> cols 128..135
            int l = gid >> 10;
            int r = gid & 1023;
            int k = r >> 3;
            int j = r & 7;
            int hh = j & 3;
            const float* av = (j < 4 ? asrc : adst) + l * 128 + hh * 32;
            const float* wp = W + l * 16384 + k * 128 + hh * 32;
            float sum = 0.f;
#pragma unroll
            for (int d = 0; d < 32; ++d) sum = fmaf(wp[d], av[d], sum);
            __bf16 h = (__bf16)sum;
            WF[foff(l, 0, 128 + j, k)] = h;
            WF[foff(l, 1, 128 + j, k)] = (__bf16)(sum - (float)h);
        }
        if (gid < 3 * 128 * 8) {            // zero pad cols 136..143
            int l = gid >> 10;
            int r = gid & 1023;
            int k = r >> 3;
            int j = r & 7;
            WF[foff(l, 0, 136 + j, k)] = (__bf16)0.f;
            WF[foff(l, 1, 136 + j, k)] = (__bf16)0.f;
        }
    } else {
        int g = tid;
        if (g < Gg) {
            int lo = 0, hi = Nn;
            while (lo < hi) { int mid = (lo + hi) >> 1; if (batch[mid] < g) lo = mid + 1; else hi = mid; }
            int lo2 = lo, hi2 = Nn;
            while (lo2 < hi2) { int mid = (lo2 + hi2) >> 1; if (batch[mid] < g + 1) lo2 = mid + 1; else hi2 = mid; }
            gcnt[g] = lo2 - lo;
        }
    }
}

// Per-bucket: LDS hist -> LDS scan -> rowstart/rowdeg write -> scatter col.
__global__ __launch_bounds__(256)
void k_bscatter2(const unsigned int* __restrict__ bkt, const int* __restrict__ bcnt,
                 int* __restrict__ rowstart, int* __restrict__ rowdeg,
                 int* __restrict__ colv, int Nn) {
    __shared__ int h[128], sc0[128], sc1[128];
    int b = blockIdx.x;
    int tid = threadIdx.x;
    if (tid < 128) h[tid] = 0;
    __syncthreads();
    int cnt = bcnt[b];
    const unsigned int* bp = bkt + (long)b * BCAP;
    for (int i = tid; i < cnt; i += 256) atomicAdd(&h[bp[i] & 127], 1);
    __syncthreads();
    int cntN = (tid < 128) ? h[tid] : 0;
    if (tid < 128) sc0[tid] = cntN;
    __syncthreads();
    int* src = sc0; int* dst = sc1;
    for (int off = 1; off < 128; off <<= 1) {
        if (tid < 128) {
            int x = src[tid];
            if (tid >= off) x += src[tid - off];
            dst[tid] = x;
        }
        __syncthreads();
        int* tw = src; src = dst; dst = tw;
    }
    int node = b * 128 + tid;
    if (tid < 128) {
        int st = b * BCAP + (src[tid] - cntN);
        h[tid] = st;
        if (node < Nn) { rowstart[node] = st; rowdeg[node] = cntN; }
    }
    __syncthreads();
    for (int i = tid; i < cnt; i += 256) {
        unsigned int e = bp[i];
        int pos = atomicAdd(&h[e & 127], 1);
        colv[pos] = (int)(e >> 7);
    }
}

// MFMA GEMM v5 (unchanged from R17).
__global__ __launch_bounds__(256, 4)
void k_gemm_mfma(const float* __restrict__ X, const __bf16* __restrict__ WF,
                 __half* __restrict__ Hout,
                 float* __restrict__ as_, float* __restrict__ ad_, int Nn) {
    int t = threadIdx.x;
    int w = t >> 6;
    int lane = t & 63;
    int li = lane & 15;
    int b  = lane >> 4;
    long row = (long)blockIdx.x * 64 + w * 16 + li;
    long rA = (row > Nn - 1) ? (Nn - 1) : row;

    f32x4 acc[9];
#pragma unroll
    for (int ct = 0; ct < 9; ++ct) acc[ct] = (f32x4){0.f, 0.f, 0.f, 0.f};

#pragma unroll
    for (int ks = 0; ks < 4; ++ks) {
        int k0 = ks * 32 + 8 * b;
        const float* xp = X + rA * 128 + k0;
        float4 f0 = *(const float4*)xp;
        float4 f1 = *(const float4*)(xp + 4);
        float af[8] = {f0.x, f0.y, f0.z, f0.w, f1.x, f1.y, f1.z, f1.w};
        bf16x8 ahi, alo;
#pragma unroll
        for (int j = 0; j < 8; ++j) {
            __bf16 h = (__bf16)af[j];
            ahi[j] = h;
            alo[j] = (__bf16)(af[j] - (float)h);
        }
        const __bf16* wk = WF + (ks * 18) * 512 + lane * 8;
#pragma unroll
        for (int ct = 0; ct < 9; ++ct) {
            bf16x8 bhi = *(const bf16x8*)(wk + ct * 512);
            bf16x8 blo = *(const bf16x8*)(wk + (9 + ct) * 512);
            acc[ct] = __builtin_amdgcn_mfma_f32_16x16x32_bf16(bhi, ahi, acc[ct], 0, 0, 0);
            acc[ct] = __builtin_amdgcn_mfma_f32_16x16x32_bf16(bhi, alo, acc[ct], 0, 0, 0);
            acc[ct] = __builtin_amdgcn_mfma_f32_16x16x32_bf16(blo, ahi, acc[ct], 0, 0, 0);
        }
    }

    if (row < Nn) {
        __half* op = Hout + row * 128 + 4 * b;
#pragma unroll
        for (int ct = 0; ct < 8; ++ct) {
            union { __half2 h2[2]; uint2 u; } pk;
            pk.h2[0] = __floats2half2_rn(acc[ct][0], acc[ct][1]);
            pk.h2[1] = __floats2half2_rn(acc[ct][2], acc[ct][3]);
            *(uint2*)(op + ct * 16) = pk.u;
        }
        if (b == 0)
            *(float4*)(as_ + 4 * row) = make_float4(acc[8][0], acc[8][1],
                                                    acc[8][2], acc[8][3]);
        else if (b == 1)
            *(float4*)(ad_ + 4 * row) = make_float4(acc[8][0], acc[8][1],
                                                    acc[8][2], acc[8][3]);
    }
}

#define LEAKY(x) ((x) > 0.f ? (x) : 0.2f * (x))

// Full-wave path for one node (deg<=64). R12 core; writes 128 floats to orow
// (global Xout row or LDS s_out row via generic pointer).
__device__ __forceinline__ void agg_full(
    const __half* __restrict__ Hb, const float* __restrict__ as_,
    const float* __restrict__ ad_, const int* __restrict__ col,
    const float* __restrict__ bias, const float* __restrict__ bn_mul,
    const float* __restrict__ bn_add, int2 (*spk)[4],
    int n, int start, int deg, int lane, float* orow) {
    int hh = lane & 3;
    int slot = lane >> 2;
    float adn = ad_[4 * n + hh];
    float esc[4]; int scl[4];
#pragma unroll
    for (int c = 0; c < 4; ++c) {
        int eidx = (c << 4) + slot;
        float e = -1e30f; int s = 0;
        if (eidx < deg) {
            s = col[start + eidx];
            e = LEAKY(as_[4 * s + hh] + adn);
        }
        esc[c] = e; scl[c] = s;
    }
    float m = fmaxf(fmaxf(esc[0], esc[1]), fmaxf(esc[2], esc[3]));
#pragma unroll
    for (int msk = 4; msk < 64; msk <<= 1) m = fmaxf(m, __shfl_xor(m, msk, 64));
    float p[4];
    float den = 0.f;
#pragma unroll
    for (int c = 0; c < 4; ++c) { p[c] = __expf(esc[c] - m); den += p[c]; }
#pragma unroll
    for (int msk = 4; msk < 64; msk <<= 1) den += __shfl_xor(den, msk, 64);
    float inv = 1.f / (den + 1e-16f);
#pragma unroll
    for (int c = 0; c < 4; ++c) {
        int2 pk;
        pk.x = scl[c] << 8;
        pk.y = __float_as_int(p[c] * inv);
        spk[(c << 4) + slot][hh] = pk;
    }

    int quarter = lane >> 4;
    int li = lane & 15;
    int hB = li >> 2;
    int cByte = li << 4;
    const char* hb8 = (const char*)Hb;
    float acc[8];
#pragma unroll
    for (int i = 0; i < 8; ++i) acc[i] = 0.f;

    int nit = (deg + 7) >> 3;
    int2 pk0 = spk[quarter][hB];
    int2 pk1 = spk[quarter + 4][hB];
    float a0 = __int_as_float(pk0.y);
    float a1 = __int_as_float(pk1.y);
    u32x4 r0 = *(const u32x4*)(hb8 + pk0.x + cByte);
    u32x4 r1 = *(const u32x4*)(hb8 + pk1.x + cByte);
    for (int it = 1; it < nit; ++it) {
        int e0 = (it << 3) + quarter;
        int2 q0 = spk[e0][hB];
        int2 q1 = spk[e0 + 4][hB];
        u32x4 t0 = *(const u32x4*)(hb8 + q0.x + cByte);
        u32x4 t1 = *(const u32x4*)(hb8 + q1.x + cByte);
        const __half* h0 = (const __half*)&r0;
        const __half* h1 = (const __half*)&r1;
#pragma unroll
        for (int q = 0; q < 8; ++q) {
            acc[q] = fmaf(__half2float(h0[q]), a0, acc[q]);
            acc[q] = fmaf(__half2float(h1[q]), a1, acc[q]);
        }
        r0 = t0; r1 = t1;
        a0 = __int_as_float(q0.y);
        a1 = __int_as_float(q1.y);
    }
    {
        const __half* h0 = (const __half*)&r0;
        const __half* h1 = (const __half*)&r1;
#pragma unroll
        for (int q = 0; q < 8; ++q) {
            acc[q] = fmaf(__half2float(h0[q]), a0, acc[q]);
            acc[q] = fmaf(__half2float(h1[q]), a1, acc[q]);
        }
    }
#pragma unroll
    for (int i = 0; i < 8; ++i) {
        float v = acc[i];
        v += __shfl_xor(v, 16, 64);
        v += __shfl_xor(v, 32, 64);
        acc[i] = v;
    }
    if (lane < 16) {
        int c0 = li << 3;
#pragma unroll
        for (int i = 0; i < 8; ++i) {
            float v = fmaxf(acc[i] + bias[c0 + i], 0.f);
            orow[c0 + i] = fmaf(v, bn_mul[c0 + i], bn_add[c0 + i]);
        }
    }
}

// 3-pass path for deg>64.
__device__ __forceinline__ void agg_big(
    const __half* __restrict__ Hb, const float* __restrict__ as_,
    const float* __restrict__ ad_, const int* __restrict__ col,
    const float* __restrict__ bias, const float* __restrict__ bn_mul,
    const float* __restrict__ bn_add,
    int n, int start, int deg, int lane, float* orow) {
    int end = start + deg;
    int hh = lane & 3;
    float adn = ad_[n * 4 + hh];
    float m = -1e30f;
    for (int base = start; base < end; base += 16) {
        int idx = base + (lane >> 2);
        float sc = -1e30f;
        if (idx < end) {
            int s = col[idx];
            sc = LEAKY(as_[s * 4 + hh] + adn);
        }
        m = fmaxf(m, sc);
    }
    for (int msk = 4; msk < 64; msk <<= 1) m = fmaxf(m, __shfl_xor(m, msk, 64));
    float den = 0.f;
    for (int base = start; base < end; base += 16) {
        int idx = base + (lane >> 2);
        if (idx < end) {
            int s = col[idx];
            float e = LEAKY(as_[s * 4 + hh] + adn);
            den += __expf(e - m);
        }
    }
    for (int msk = 4; msk < 64; msk <<= 1) den += __shfl_xor(den, msk, 64);
    int hB = lane >> 4;
    float mB   = __shfl(m, hB, 64);
    float invB = 1.f / (__shfl(den, hB, 64) + 1e-16f);
    float adB  = ad_[n * 4 + hB];
    int c0 = lane << 1;
    float acc0 = 0.f, acc1 = 0.f;
    for (int i = start; i < end; ++i) {
        int s = col[i];
        float e = LEAKY(as_[s * 4 + hB] + adB);
        float alpha = __expf(e - mB) * invB;
        float2 hv = __half22float2(*(const __half2*)(Hb + (long)s * 128 + c0));
        acc0 = fmaf(hv.x, alpha, acc0);
        acc1 = fmaf(hv.y, alpha, acc1);
    }
    float v0 = fmaxf(acc0 + bias[c0], 0.f);
    float v1 = fmaxf(acc1 + bias[c0 + 1], 0.f);
    orow[c0]     = fmaf(v0, bn_mul[c0], bn_add[c0]);
    orow[c0 + 1] = fmaf(v1, bn_mul[c0 + 1], bn_add[c0 + 1]);
}

// Dual-node aggregate: 8 nodes/block, 2 per wave (lanes 0-31 / 32-63) when
// both deg<=32; else sequential full-wave / 3-pass fallback per node.
template <bool POOL>
__global__ __launch_bounds__(256)
void k_aggregate(const __half* __restrict__ Hb, const float* __restrict__ as_,
                 const float* __restrict__ ad_, const int* __restrict__ rowstart,
                 const int* __restrict__ rowdeg,
                 const int* __restrict__ col, const float* __restrict__ bias,
                 const float* __restrict__ bn_mul, const float* __restrict__ bn_add,
                 float* __restrict__ Xout, const int* __restrict__ batch,
                 float* __restrict__ gsum, int Nn) {
    __shared__ int2 s_pk[4][64][4];    // per wave: 2 halves x 32 slots (or 64 flat)
    __shared__ float s_out[POOL ? 8 : 1][POOL ? 128 : 1];
    __shared__ int s_g[POOL ? 8 : 1];
    int w = threadIdx.x >> 6;
    int lane = threadIdx.x & 63;
    int half = lane >> 5;
    int hl = lane & 31;
    int nbase = (blockIdx.x << 3) + (w << 1);
    int n = nbase + half;
    bool active = n < Nn;
    if (!POOL && nbase >= Nn) return;
    if (POOL && hl == 0) s_g[(w << 1) + half] = active ? batch[n] : -1;

    int start = active ? rowstart[n] : 0;
    int deg   = active ? rowdeg[n]   : 0;
    int degO  = __shfl_xor(deg, 32, 64);
    int degmax = deg > degO ? deg : degO;

    if (degmax <= 32) {
        // ---- dual phase A: half-wave softmax (8 slots x 4 heads x 4 chunks) ----
        int hh = hl & 3;
        int slot = hl >> 2;              // 0..7
        float adn = active ? ad_[4 * n + hh] : 0.f;
        float esc[4]; int scl[4];
#pragma unroll
        for (int c = 0; c < 4; ++c) {
            int eidx = (c << 3) + slot;
            float e = -1e30f; int s = 0;
            if (eidx < deg) {
                s = col[start + eidx];
                e = LEAKY(as_[4 * s + hh] + adn);
            }
            esc[c] = e; scl[c] = s;
        }
        float m = fmaxf(fmaxf(esc[0], esc[1]), fmaxf(esc[2], esc[3]));
#pragma unroll
        for (int msk = 4; msk < 32; msk <<= 1) m = fmaxf(m, __shfl_xor(m, msk, 64));
        float p[4];
        float den = 0.f;
#pragma unroll
        for (int c = 0; c < 4; ++c) { p[c] = __expf(esc[c] - m); den += p[c]; }
#pragma unroll
        for (int msk = 4; msk < 32; msk <<= 1) den += __shfl_xor(den, msk, 64);
        float inv = 1.f / (den + 1e-16f);
        int hbase = half << 5;
#pragma unroll
        for (int c = 0; c < 4; ++c) {
            int2 pk;
            pk.x = scl[c] << 8;
            pk.y = __float_as_int(p[c] * inv);
            s_pk[w][hbase + (c << 3) + slot][hh] = pk;
        }

        // ---- dual phase B: 4 edges/iter per half (2 quarters x 2) ----
        int q = (hl >> 4) & 1;
        int li = hl & 15;
        int hB = li >> 2;
        int cByte = li << 4;
        const char* hb8 = (const char*)Hb;
        float acc[8];
#pragma unroll
        for (int i = 0; i < 8; ++i) acc[i] = 0.f;

        int nit = (degmax + 3) >> 2;     // uniform across wave
        int2 pk0 = s_pk[w][hbase + q][hB];
        int2 pk1 = s_pk[w][hbase + q + 2][hB];
        float a0 = __int_as_float(pk0.y);
        float a1 = __int_as_float(pk1.y);
        u32x4 r0 = *(const u32x4*)(hb8 + pk0.x + cByte);
        u32x4 r1 = *(const u32x4*)(hb8 + pk1.x + cByte);
        for (int it = 1; it < nit; ++it) {
            int e0 = (it << 2) + q;
            int2 q0 = s_pk[w][hbase + e0][hB];
            int2 q1 = s_pk[w][hbase + e0 + 2][hB];
            u32x4 t0 = *(const u32x4*)(hb8 + q0.x + cByte);
            u32x4 t1 = *(const u32x4*)(hb8 + q1.x + cByte);
            const __half* h0 = (const __half*)&r0;
            const __half* h1 = (const __half*)&r1;
#pragma unroll
            for (int qq = 0; qq < 8; ++qq) {
                acc[qq] = fmaf(__half2float(h0[qq]), a0, acc[qq]);
                acc[qq] = fmaf(__half2float(h1[qq]), a1, acc[qq]);
            }
            r0 = t0; r1 = t1;
            a0 = __int_as_float(q0.y);
            a1 = __int_as_float(q1.y);
        }
        {
            const __half* h0 = (const __half*)&r0;
            const __half* h1 = (const __half*)&r1;
#pragma unroll
            for (int qq = 0; qq < 8; ++qq) {
                acc[qq] = fmaf(__half2float(h0[qq]), a0, acc[qq]);
                acc[qq] = fmaf(__half2float(h1[qq]), a1, acc[qq]);
            }
        }
#pragma unroll
        for (int i = 0; i < 8; ++i) acc[i] += __shfl_xor(acc[i], 16, 64);

        if (hl < 16) {
            int c0 = li << 3;
            if (active) {
#pragma unroll
                for (int i = 0; i < 8; ++i) {
                    float v = fmaxf(acc[i] + bias[c0 + i], 0.f);
                    v = fmaf(v, bn_mul[c0 + i], bn_add[c0 + i]);
                    if (!POOL) Xout[(long)n * 128 + c0 + i] = v;
                    else       s_out[(w << 1) + half][c0 + i] = v;
                }
            } else if (POOL) {
#pragma unroll
                for (int i = 0; i < 8; ++i) s_out[(w << 1) + half][c0 + i] = 0.f;
            }
        }
    } else {
        // ---- fallback: sequential per node with full wave ----
        for (int h2 = 0; h2 < 2; ++h2) {
            int nn = nbase + h2;
            int st2 = __shfl(start, h2 << 5, 64);
            int dg2 = __shfl(deg, h2 << 5, 64);
            bool act2 = nn < Nn;
            float* orow;
            if (POOL) orow = &s_out[(w << 1) + h2][0];
            else      orow = Xout + (long)nn * 128;
            if (act2) {
                if (dg2 <= 64)
                    agg_full(Hb, as_, ad_, col, bias, bn_mul, bn_add,
                             s_pk[w], nn, st2, dg2, lane, orow);
                else
                    agg_big(Hb, as_, ad_, col, bias, bn_mul, bn_add,
                            nn, st2, dg2, lane, orow);
            } else if (POOL) {
                for (int i = lane; i < 128; i += 64) orow[i] = 0.f;
            }
        }
    }

    if (POOL) {
        __syncthreads();
        int tid = threadIdx.x;
        if (tid < 128) {
            int g0 = s_g[0];
            bool same = true;
#pragma unroll
            for (int k = 1; k < 8; ++k) same = same && (s_g[k] == g0);
            if (same) {
                if (g0 >= 0) {
                    float s8 = 0.f;
#pragma unroll
                    for (int k = 0; k < 8; ++k) s8 += s_out[k][tid];
                    atomicAdd(&gsum[g0 * 128 + tid], s8);
                }
            } else {
#pragma unroll
                for (int k = 0; k < 8; ++k)
                    if (s_g[k] >= 0) atomicAdd(&gsum[s_g[k] * 128 + tid], s_out[k][tid]);
            }
        }
    }
}

__global__ __launch_bounds__(64)
void k_head(const float* __restrict__ gsum, const int* __restrict__ gcnt,
            const float* __restrict__ Wh1, const float* __restrict__ bh1,
            const float* __restrict__ Wh2, const float* __restrict__ bh2,
            float* __restrict__ outp) {
    __shared__ float pooled[128];
    int g = blockIdx.x;
    int j = threadIdx.x;
    int cnt = gcnt[g];
    float inv = 1.f / (float)(cnt > 1 ? cnt : 1);
    pooled[j]      = gsum[g * 128 + j] * inv;
    pooled[j + 64] = gsum[g * 128 + 64 + j] * inv;
    __syncthreads();
    float acc = bh1[j];
    for (int k = 0; k < 128; ++k) acc = fmaf(pooled[k], Wh1[k * 64 + j], acc);
    acc = fmaxf(acc, 0.f);
    float prod = acc * Wh2[j];
    for (int msk = 1; msk < 64; msk <<= 1) prod += __shfl_xor(prod, msk, 64);
    if (j == 0) outp[g] = prod + bh2[0];
}

extern "C" void kernel_launch(void* const* d_in, const int* in_sizes, int n_in,
                              void* d_out, int out_size, void* d_ws, size_t ws_size,
                              hipStream_t stream) {
    const float* x       = (const float*)d_in[0];
    const int*   ei      = (const int*)d_in[1];
    const int*   batch   = (const int*)d_in[2];
    const float* W       = (const float*)d_in[3];
    const float* att_src = (const float*)d_in[4];
    const float* att_dst = (const float*)d_in[5];
    const float* bias    = (const float*)d_in[6];
    const float* gamma   = (const float*)d_in[7];
    const float* beta    = (const float*)d_in[8];
    const float* bn_mean = (const float*)d_in[9];
    const float* bn_var  = (const float*)d_in[10];
    const float* Wh1     = (const float*)d_in[11];
    const float* bh1     = (const float*)d_in[12];
    const float* Wh2     = (const float*)d_in[13];
    const float* bh2     = (const float*)d_in[14];
    float* out = (float*)d_out;

    const int Nn = in_sizes[0] / 128;
    const int Ne = in_sizes[1] / 2;
    const int Gg = out_size;
    const int nnz = Ne + Nn;
    const int nbkt = (Nn + 127) / 128;
    const int nBB = (nnz + 2047) / 2048;

    char* ws = (char*)d_ws;
    size_t off = 0;
    auto alloc = [&](size_t bytes) -> char* {
        char* p = ws + off;
        off = (off + bytes + 255) & ~(size_t)255;
        return p;
    };
    float*        bufA     = (float*)alloc((size_t)Nn * 128 * 4);
    __half*       bufH     = (__half*)alloc((size_t)Nn * 128 * 2);
    float*        as_      = (float*)alloc((size_t)Nn * 4 * 4);
    float*        ad_      = (float*)alloc((size_t)Nn * 4 * 4);
    int*          rowstart = (int*)alloc((size_t)Nn * 4);
    int*          rowdeg   = (int*)alloc((size_t)Nn * 4);
    int*          col      = (int*)alloc((size_t)nbkt * BCAP * 4);
    float*        bn_mul   = (float*)alloc(384 * 4);
    float*        bn_add   = (float*)alloc(384 * 4);
    float*        gsum     = (float*)alloc((size_t)Gg * 128 * 4);
    int*          gcnt     = (int*)alloc((size_t)Gg * 4);
    __bf16*       WtF      = (__bf16*)alloc((size_t)3 * WLSZ * 2);
    unsigned int* bkt      = (unsigned int*)alloc((size_t)nbkt * BCAP * 4);
    int*          bcnt     = (int*)alloc((size_t)nbkt * 4);

    // ---- fused front-end (prep + bucket + gcnt) + bucket scatter ----
    hipMemsetAsync(bcnt, 0, (size_t)nbkt * 4, stream);
    k_front<<<nBB + 193, 256, 0, stream>>>(ei, bkt, bcnt, gsum, gcnt, batch,
                                           gamma, beta, bn_mean, bn_var,
                                           bn_mul, bn_add, W, att_src, att_dst,
                                           WtF, Ne, Nn, nbkt, Gg, nBB);
    k_bscatter2<<<nbkt, 256, 0, stream>>>(bkt, bcnt, rowstart, rowdeg, col, Nn);

    // ---- 3 GAT layers (layer 3 fuses mean-pool) ----
    const float* cur = x;
    for (int l = 0; l < 3; ++l) {
        k_gemm_mfma<<<(Nn + 63) / 64, 256, 0, stream>>>(cur, WtF + l * WLSZ,
                                                        bufH, as_, ad_, Nn);
        if (l < 2)
            k_aggregate<false><<<(Nn + 7) / 8, 256, 0, stream>>>(
                bufH, as_, ad_, rowstart, rowdeg, col, bias + l * 128,
                bn_mul + l * 128, bn_add + l * 128, bufA, batch, gsum, Nn);
        else
            k_aggregate<true><<<(Nn + 7) / 8, 256, 0, stream>>>(
                bufH, as_, ad_, rowstart, rowdeg, col, bias + l * 128,
                bn_mul + l * 128, bn_add + l * 128, bufA, batch, gsum, Nn);
        cur = bufA;
    }

    // ---- head ----
    k_head<<<Gg, 64, 0, stream>>>(gsum, gcnt, Wh1, bh1, Wh2, bh2, out);
}

// Round 13
// 493.039 us; speedup vs baseline: 1.0277x; 1.0277x over previous
//
#include <hip/hip_runtime.h>
#include <hip/hip_fp16.h>

// ---------------------------------------------------------------------------
// GATNet forward: 3x (GATConv -> ReLU -> BN) -> mean-pool -> MLP(128->64->1)
// N=100000, E=1.6M (+N self loops), HID=128, H=4, D=32, G=128.
// R24 = R20 revert (504.2us verified; cooperative mega-kernel failed
// correctness twice with identical absmax -> abandoned per decision rule)
// + ONE safe merge: k_bscatter2 and layer-0 GEMM are both independent given
// k_front, so they share one kernel with disjoint blockIdx ranges
// (blocks [0,nbkt) = bscatter, [nbkt,nbkt+ntile) = gemm l=0). 10->9
// dispatches, no new synchronization, bodies R20-verbatim.
// ---------------------------------------------------------------------------

typedef __bf16 bf16x8 __attribute__((ext_vector_type(8)));
typedef float  f32x4  __attribute__((ext_vector_type(4)));
typedef unsigned int u32x4 __attribute__((ext_vector_type(4)));

#define WLSZ 36864  // per-layer fragment-linear W: 18 tiles * 4 ks * 64 lanes * 8
#define MAXBKT 800  // >= ceil(Nn/128); Nn=100000 -> 782
#define BCAP   4096 // bucket capacity; mean 2176, max ~2400

#define LEAKY(x) ((x) > 0.f ? (x) : 0.2f * (x))

// fragment-linear offset for W buffer (see R14 notes).
__device__ __forceinline__ int foff(int l, int d, int n, int k) {
    int ct = n >> 4, li = n & 15;
    int ks = k >> 5, bq = (k >> 3) & 3, j = k & 7;
    return l * WLSZ + (((ks * 18) + d * 9 + ct) * 64 + (bq << 4) + li) * 8 + j;
}

// Fused front-end. Blocks [0, nBB): edge bucketing (+ gsum zero).
// Blocks [nBB, nBB+192): param prep. Block nBB+192: gcnt binary search.
__global__ __launch_bounds__(256)
void k_front(const int* __restrict__ ei, unsigned int* __restrict__ bkt,
             int* __restrict__ bcnt, float* __restrict__ gsum,
             int* __restrict__ gcnt, const int* __restrict__ batch,
             const float* __restrict__ gamma, const float* __restrict__ beta,
             const float* __restrict__ mean, const float* __restrict__ var,
             float* __restrict__ bn_mul, float* __restrict__ bn_add,
             const float* __restrict__ W, const float* __restrict__ asrc,
             const float* __restrict__ adst, __bf16* __restrict__ WF,
             int Ne, int Nn, int nbkt, int Gg, int nBB) {
    __shared__ int lcnt[MAXBKT];
    __shared__ int lbase[MAXBKT];
    int bb = blockIdx.x;
    int tid = threadIdx.x;

    if (bb < nBB) {
        int gid = bb * 256 + tid;
        if (gid < Gg * 128) gsum[gid] = 0.f;
        for (int i = tid; i < nbkt; i += 256) lcnt[i] = 0;
        __syncthreads();
        int chunk0 = bb * 2048;
        int nnz = Ne + Nn;
        for (int i = 0; i < 8; ++i) {
            int e = chunk0 + i * 256 + tid;
            if (e < nnz) {
                int d = (e < Ne) ? ei[Ne + e] : (e - Ne);
                atomicAdd(&lcnt[d >> 7], 1);
            }
        }
        __syncthreads();
        for (int b = tid; b < nbkt; b += 256) {
            int c = lcnt[b];
            lbase[b] = (c > 0) ? atomicAdd(&bcnt[b], c) : 0;
            lcnt[b] = 0;
        }
        __syncthreads();
        for (int i = 0; i < 8; ++i) {
            int e = chunk0 + i * 256 + tid;
            if (e < nnz) {
                int s, d;
                if (e < Ne) { s = ei[e]; d = ei[Ne + e]; }
                else        { s = e - Ne; d = e - Ne; }
                int b = d >> 7;
                int r = atomicAdd(&lcnt[b], 1);
                bkt[(long)b * BCAP + lbase[b] + r] = ((unsigned)s << 7) | (unsigned)(d & 127);
            }
        }
    } else if (bb < nBB + 192) {
        int gid = (bb - nBB) * 256 + tid;
        if (gid < 384) {
            float sc = gamma[gid] / sqrtf(var[gid] + 1e-5f);
            bn_mul[gid] = sc;
            bn_add[gid] = beta[gid] - mean[gid] * sc;
        }
        if (gid < 3 * 128 * 128) {
            int l = gid >> 14;
            int k = (gid >> 7) & 127;
            int n = gid & 127;
            float f = W[gid];
            __bf16 h = (__bf16)f;
            WF[foff(l, 0, n, k)] = h;
            WF[foff(l, 1, n, k)] = (__bf16)(f - (float)h);
        }
        if (gid < 3 * 128 * 8) {            // wa projections -> cols 128..135
            int l = gid >> 10;
            int r = gid & 1023;
            int k = r >> 3;
            int j = r & 7;
            int hh = j & 3;
            const float* av = (j < 4 ? asrc : adst) + l * 128 + hh * 32;
            const float* wp = W + l * 16384 + k * 128 + hh * 32;
            float sum = 0.f;
#pragma unroll
            for (int d = 0; d < 32; ++d) sum = fmaf(wp[d], av[d], sum);
            __bf16 h = (__bf16)sum;
            WF[foff(l, 0, 128 + j, k)] = h;
            WF[foff(l, 1, 128 + j, k)] = (__bf16)(sum - (float)h);
        }
        if (gid < 3 * 128 * 8) {            // zero pad cols 136..143
            int l = gid >> 10;
            int r = gid & 1023;
            int k = r >> 3;
            int j = r & 7;
            WF[foff(l, 0, 136 + j, k)] = (__bf16)0.f;
            WF[foff(l, 1, 136 + j, k)] = (__bf16)0.f;
        }
    } else {
        int g = tid;
        if (g < Gg) {
            int lo = 0, hi = Nn;
            while (lo < hi) { int mid = (lo + hi) >> 1; if (batch[mid] < g) lo = mid + 1; else hi = mid; }
            int lo2 = lo, hi2 = Nn;
            while (lo2 < hi2) { int mid = (lo2 + hi2) >> 1; if (batch[mid] < g + 1) lo2 = mid + 1; else hi2 = mid; }
            gcnt[g] = lo2 - lo;
        }
    }
}

// GEMM v5 body (R20-verbatim, parameterized by tile index).
__device__ __forceinline__ void gemm_body(int tile, const float* __restrict__ X,
                                          const __bf16* __restrict__ WF,
                                          __half* __restrict__ Hout,
                                          float* __restrict__ as_,
                                          float* __restrict__ ad_, int Nn) {
    int t = threadIdx.x;
    int w = t >> 6;
    int lane = t & 63;
    int li = lane & 15;
    int b  = lane >> 4;
    long row = (long)tile * 64 + w * 16 + li;
    long rA = (row > Nn - 1) ? (Nn - 1) : row;

    f32x4 acc[9];
#pragma unroll
    for (int ct = 0; ct < 9; ++ct) acc[ct] = (f32x4){0.f, 0.f, 0.f, 0.f};

#pragma unroll
    for (int ks = 0; ks < 4; ++ks) {
        int k0 = ks * 32 + 8 * b;
        const float* xp = X + rA * 128 + k0;
        float4 f0 = *(const float4*)xp;
        float4 f1 = *(const float4*)(xp + 4);
        float af[8] = {f0.x, f0.y, f0.z, f0.w, f1.x, f1.y, f1.z, f1.w};
        bf16x8 ahi, alo;
#pragma unroll
        for (int j = 0; j < 8; ++j) {
            __bf16 h = (__bf16)af[j];
            ahi[j] = h;
            alo[j] = (__bf16)(af[j] - (float)h);
        }
        const __bf16* wk = WF + (ks * 18) * 512 + lane * 8;
#pragma unroll
        for (int ct = 0; ct < 9; ++ct) {
            bf16x8 bhi = *(const bf16x8*)(wk + ct * 512);
            bf16x8 blo = *(const bf16x8*)(wk + (9 + ct) * 512);
            acc[ct] = __builtin_amdgcn_mfma_f32_16x16x32_bf16(bhi, ahi, acc[ct], 0, 0, 0);
            acc[ct] = __builtin_amdgcn_mfma_f32_16x16x32_bf16(bhi, alo, acc[ct], 0, 0, 0);
            acc[ct] = __builtin_amdgcn_mfma_f32_16x16x32_bf16(blo, ahi, acc[ct], 0, 0, 0);
        }
    }

    if (row < Nn) {
        __half* op = Hout + row * 128 + 4 * b;
#pragma unroll
        for (int ct = 0; ct < 8; ++ct) {
            union { __half2 h2[2]; uint2 u; } pk;
            pk.h2[0] = __floats2half2_rn(acc[ct][0], acc[ct][1]);
            pk.h2[1] = __floats2half2_rn(acc[ct][2], acc[ct][3]);
            *(uint2*)(op + ct * 16) = pk.u;
        }
        if (b == 0)
            *(float4*)(as_ + 4 * row) = make_float4(acc[8][0], acc[8][1],
                                                    acc[8][2], acc[8][3]);
        else if (b == 1)
            *(float4*)(ad_ + 4 * row) = make_float4(acc[8][0], acc[8][1],
                                                    acc[8][2], acc[8][3]);
    }
}

// Merged: blocks [0,nbkt) = bscatter (R20 body); [nbkt, nbkt+ntile) = layer-0
// GEMM. Both depend only on k_front; no intra-kernel ordering needed.
__global__ __launch_bounds__(256, 4)
void k_bsgemm(const unsigned int* __restrict__ bkt, const int* __restrict__ bcnt,
              int* __restrict__ rowstart, int* __restrict__ rowdeg,
              int* __restrict__ colv,
              const float* __restrict__ X, const __bf16* __restrict__ WF,
              __half* __restrict__ Hout, float* __restrict__ as_,
              float* __restrict__ ad_, int Nn, int nbkt) {
    if (blockIdx.x >= nbkt) {
        gemm_body(blockIdx.x - nbkt, X, WF, Hout, as_, ad_, Nn);
        return;
    }
    __shared__ int h[128], sc0[128], sc1[128];
    int b = blockIdx.x;
    int tid = threadIdx.x;
    if (tid < 128) h[tid] = 0;
    __syncthreads();
    int cnt = bcnt[b];
    const unsigned int* bp = bkt + (long)b * BCAP;
    for (int i = tid; i < cnt; i += 256) atomicAdd(&h[bp[i] & 127], 1);
    __syncthreads();
    int cntN = (tid < 128) ? h[tid] : 0;
    if (tid < 128) sc0[tid] = cntN;
    __syncthreads();
    int* src = sc0; int* dst = sc1;
    for (int off = 1; off < 128; off <<= 1) {
        if (tid < 128) {
            int x = src[tid];
            if (tid >= off) x += src[tid - off];
            dst[tid] = x;
        }
        __syncthreads();
        int* tw = src; src = dst; dst = tw;
    }
    int node = b * 128 + tid;
    if (tid < 128) {
        int st = b * BCAP + (src[tid] - cntN);
        h[tid] = st;
        if (node < Nn) { rowstart[node] = st; rowdeg[node] = cntN; }
    }
    __syncthreads();
    for (int i = tid; i < cnt; i += 256) {
        unsigned int e = bp[i];
        int pos = atomicAdd(&h[e & 127], 1);
        colv[pos] = (int)(e >> 7);
    }
}

// Standalone GEMM (layers 1,2).
__global__ __launch_bounds__(256, 4)
void k_gemm_mfma(const float* __restrict__ X, const __bf16* __restrict__ WF,
                 __half* __restrict__ Hout,
                 float* __restrict__ as_, float* __restrict__ ad_, int Nn) {
    gemm_body(blockIdx.x, X, WF, Hout, as_, ad_, Nn);
}

// One wave per dst node, 4 nodes/block. R12 core. POOL=true (layer 3): skip
// Xout; block-sum the 4 node vectors in LDS, one atomicAdd/col into gsum.
template <bool POOL>
__global__ __launch_bounds__(256)
void k_aggregate(const __half* __restrict__ Hb, const float* __restrict__ as_,
                 const float* __restrict__ ad_, const int* __restrict__ rowstart,
                 const int* __restrict__ rowdeg,
                 const int* __restrict__ col, const float* __restrict__ bias,
                 const float* __restrict__ bn_mul, const float* __restrict__ bn_add,
                 float* __restrict__ Xout, const int* __restrict__ batch,
                 float* __restrict__ gsum, int Nn) {
    __shared__ int2 s_pk[4][64][4];    // {src byte-offset, alpha bits} 8 KB
    __shared__ float s_out[POOL ? 4 : 1][POOL ? 128 : 1];
    __shared__ int s_g[POOL ? 4 : 1];
    int w = threadIdx.x >> 6;
    int n = (blockIdx.x << 2) + w;
    int lane = threadIdx.x & 63;
    bool active = (n < Nn);
    if (!POOL && !active) return;
    if (POOL && lane == 0) s_g[w] = active ? batch[n] : -1;

    if (active) {
        int start = rowstart[n];
        int deg = rowdeg[n];

        if (deg <= 64) {
            // ---- phase A: lane=(slot,head), one-shot softmax ----
            int hh = lane & 3;
            int slot = lane >> 2;
            float adn = ad_[4 * n + hh];
            float esc[4]; int scl[4];
#pragma unroll
            for (int c = 0; c < 4; ++c) {
                int eidx = (c << 4) + slot;
                float e = -1e30f; int s = 0;
                if (eidx < deg) {
                    s = col[start + eidx];
                    e = LEAKY(as_[4 * s + hh] + adn);
                }
                esc[c] = e; scl[c] = s;
            }
            float m = fmaxf(fmaxf(esc[0], esc[1]), fmaxf(esc[2], esc[3]));
#pragma unroll
            for (int msk = 4; msk < 64; msk <<= 1) m = fmaxf(m, __shfl_xor(m, msk, 64));
            float p[4];
            float den = 0.f;
#pragma unroll
            for (int c = 0; c < 4; ++c) { p[c] = __expf(esc[c] - m); den += p[c]; }
#pragma unroll
            for (int msk = 4; msk < 64; msk <<= 1) den += __shfl_xor(den, msk, 64);
            float inv = 1.f / (den + 1e-16f);
#pragma unroll
            for (int c = 0; c < 4; ++c) {
                int2 pk;
                pk.x = scl[c] << 8;
                pk.y = __float_as_int(p[c] * inv);
                s_pk[w][(c << 4) + slot][hh] = pk;
            }

            // ---- phase B: pipelined, 8 edges/iter, 16B/lane ----
            int quarter = lane >> 4;
            int li = lane & 15;
            int hB = li >> 2;
            int cByte = li << 4;
            const char* hb8 = (const char*)Hb;
            float acc[8];
#pragma unroll
            for (int i = 0; i < 8; ++i) acc[i] = 0.f;

            int nit = (deg + 7) >> 3;
            int2 pk0 = s_pk[w][quarter][hB];
            int2 pk1 = s_pk[w][quarter + 4][hB];
            float a0 = __int_as_float(pk0.y);
            float a1 = __int_as_float(pk1.y);
            u32x4 r0 = *(const u32x4*)(hb8 + pk0.x + cByte);
            u32x4 r1 = *(const u32x4*)(hb8 + pk1.x + cByte);
            for (int it = 1; it < nit; ++it) {
                int e0 = (it << 3) + quarter;
                int2 q0 = s_pk[w][e0][hB];
                int2 q1 = s_pk[w][e0 + 4][hB];
                u32x4 t0 = *(const u32x4*)(hb8 + q0.x + cByte);
                u32x4 t1 = *(const u32x4*)(hb8 + q1.x + cByte);
                const __half* h0 = (const __half*)&r0;
                const __half* h1 = (const __half*)&r1;
#pragma unroll
                for (int q = 0; q < 8; ++q) {
                    acc[q] = fmaf(__half2float(h0[q]), a0, acc[q]);
                    acc[q] = fmaf(__half2float(h1[q]), a1, acc[q]);
                }
                r0 = t0; r1 = t1;
                a0 = __int_as_float(q0.y);
                a1 = __int_as_float(q1.y);
            }
            {
                const __half* h0 = (const __half*)&r0;
                const __half* h1 = (const __half*)&r1;
#pragma unroll
                for (int q = 0; q < 8; ++q) {
                    acc[q] = fmaf(__half2float(h0[q]), a0, acc[q]);
                    acc[q] = fmaf(__half2float(h1[q]), a1, acc[q]);
                }
            }
#pragma unroll
            for (int i = 0; i < 8; ++i) {
                float v = acc[i];
                v += __shfl_xor(v, 16, 64);
                v += __shfl_xor(v, 32, 64);
                acc[i] = v;
            }
            if (lane < 16) {
                int c0 = li << 3;
                float4 bz0 = *(const float4*)(bias + c0);
                float4 bz1 = *(const float4*)(bias + c0 + 4);
                float4 m0 = *(const float4*)(bn_mul + c0);
                float4 m1 = *(const float4*)(bn_mul + c0 + 4);
                float4 a0v = *(const float4*)(bn_add + c0);
                float4 a1v = *(const float4*)(bn_add + c0 + 4);
                float4 o0, o1;
                o0.x = fmaf(fmaxf(acc[0] + bz0.x, 0.f), m0.x, a0v.x);
                o0.y = fmaf(fmaxf(acc[1] + bz0.y, 0.f), m0.y, a0v.y);
                o0.z = fmaf(fmaxf(acc[2] + bz0.z, 0.f), m0.z, a0v.z);
                o0.w = fmaf(fmaxf(acc[3] + bz0.w, 0.f), m0.w, a0v.w);
                o1.x = fmaf(fmaxf(acc[4] + bz1.x, 0.f), m1.x, a1v.x);
                o1.y = fmaf(fmaxf(acc[5] + bz1.y, 0.f), m1.y, a1v.y);
                o1.z = fmaf(fmaxf(acc[6] + bz1.z, 0.f), m1.z, a1v.z);
                o1.w = fmaf(fmaxf(acc[7] + bz1.w, 0.f), m1.w, a1v.w);
                if (!POOL) {
                    *(float4*)(Xout + (long)n * 128 + c0)     = o0;
                    *(float4*)(Xout + (long)n * 128 + c0 + 4) = o1;
                } else {
                    *(float4*)(&s_out[w][c0])     = o0;
                    *(float4*)(&s_out[w][c0 + 4]) = o1;
                }
            }
        } else {
            // ---- fallback (deg > 64): 3-pass ----
            int end = start + deg;
            int hh = lane & 3;
            float adn = ad_[n * 4 + hh];
            float m = -1e30f;
            for (int base = start; base < end; base += 16) {
                int idx = base + (lane >> 2);
                float sc = -1e30f;
                if (idx < end) {
                    int s = col[idx];
                    sc = LEAKY(as_[s * 4 + hh] + adn);
                }
                m = fmaxf(m, sc);
            }
            for (int msk = 4; msk < 64; msk <<= 1) m = fmaxf(m, __shfl_xor(m, msk, 64));
            float den = 0.f;
            for (int base = start; base < end; base += 16) {
                int idx = base + (lane >> 2);
                if (idx < end) {
                    int s = col[idx];
                    float e = LEAKY(as_[s * 4 + hh] + adn);
                    den += __expf(e - m);
                }
            }
            for (int msk = 4; msk < 64; msk <<= 1) den += __shfl_xor(den, msk, 64);
            int hB = lane >> 4;
            float mB   = __shfl(m, hB, 64);
            float invB = 1.f / (__shfl(den, hB, 64) + 1e-16f);
            float adB  = ad_[n * 4 + hB];
            int c0 = lane << 1;
            float acc0 = 0.f, acc1 = 0.f;
            for (int i = start; i < end; ++i) {
                int s = col[i];
                float e = LEAKY(as_[s * 4 + hB] + adB);
                float alpha = __expf(e - mB) * invB;
                float2 hv = __half22float2(*(const __half2*)(Hb + (long)s * 128 + c0));
                acc0 = fmaf(hv.x, alpha, acc0);
                acc1 = fmaf(hv.y, alpha, acc1);
            }
            float v0 = fmaxf(acc0 + bias[c0], 0.f);
            float v1 = fmaxf(acc1 + bias[c0 + 1], 0.f);
            v0 = fmaf(v0, bn_mul[c0], bn_add[c0]);
            v1 = fmaf(v1, bn_mul[c0 + 1], bn_add[c0 + 1]);
            if (!POOL) {
                *(float2*)(Xout + (long)n * 128 + c0) = make_float2(v0, v1);
            } else {
                s_out[w][c0]     = v0;
                s_out[w][c0 + 1] = v1;
            }
        }
    } else if (POOL) {
        if (lane < 16) {
            int c0 = (lane & 15) << 3;
#pragma unroll
            for (int i = 0; i < 8; ++i) s_out[w][c0 + i] = 0.f;
        }
    }

    if (POOL) {
        __syncthreads();
        int tid = threadIdx.x;
        if (tid < 128) {
            int g0 = s_g[0], g1 = s_g[1], g2 = s_g[2], g3 = s_g[3];
            float v0 = s_out[0][tid], v1 = s_out[1][tid];
            float v2 = s_out[2][tid], v3 = s_out[3][tid];
            if (g0 == g1 && g1 == g2 && g2 == g3) {
                if (g0 >= 0) atomicAdd(&gsum[g0 * 128 + tid], v0 + v1 + v2 + v3);
            } else {
                if (g0 >= 0) atomicAdd(&gsum[g0 * 128 + tid], v0);
                if (g1 >= 0) atomicAdd(&gsum[g1 * 128 + tid], v1);
                if (g2 >= 0) atomicAdd(&gsum[g2 * 128 + tid], v2);
                if (g3 >= 0) atomicAdd(&gsum[g3 * 128 + tid], v3);
            }
        }
    }
}

__global__ __launch_bounds__(64)
void k_head(const float* __restrict__ gsum, const int* __restrict__ gcnt,
            const float* __restrict__ Wh1, const float* __restrict__ bh1,
            const float* __restrict__ Wh2, const float* __restrict__ bh2,
            float* __restrict__ outp) {
    __shared__ float pooled[128];
    int g = blockIdx.x;
    int j = threadIdx.x;
    int cnt = gcnt[g];
    float inv = 1.f / (float)(cnt > 1 ? cnt : 1);
    pooled[j]      = gsum[g * 128 + j] * inv;
    pooled[j + 64] = gsum[g * 128 + 64 + j] * inv;
    __syncthreads();
    float acc = bh1[j];
    for (int k = 0; k < 128; ++k) acc = fmaf(pooled[k], Wh1[k * 64 + j], acc);
    acc = fmaxf(acc, 0.f);
    float prod = acc * Wh2[j];
    for (int msk = 1; msk < 64; msk <<= 1) prod += __shfl_xor(prod, msk, 64);
    if (j == 0) outp[g] = prod + bh2[0];
}

extern "C" void kernel_launch(void* const* d_in, const int* in_sizes, int n_in,
                              void* d_out, int out_size, void* d_ws, size_t ws_size,
                              hipStream_t stream) {
    const float* x       = (const float*)d_in[0];
    const int*   ei      = (const int*)d_in[1];
    const int*   batch   = (const int*)d_in[2];
    const float* W       = (const float*)d_in[3];
    const float* att_src = (const float*)d_in[4];
    const float* att_dst = (const float*)d_in[5];
    const float* bias    = (const float*)d_in[6];
    const float* gamma   = (const float*)d_in[7];
    const float* beta    = (const float*)d_in[8];
    const float* bn_mean = (const float*)d_in[9];
    const float* bn_var  = (const float*)d_in[10];
    const float* Wh1     = (const float*)d_in[11];
    const float* bh1     = (const float*)d_in[12];
    const float* Wh2     = (const float*)d_in[13];
    const float* bh2     = (const float*)d_in[14];
    float* out = (float*)d_out;

    const int Nn = in_sizes[0] / 128;
    const int Ne = in_sizes[1] / 2;
    const int Gg = out_size;
    const int nnz = Ne + Nn;
    const int nbkt = (Nn + 127) / 128;
    const int nBB = (nnz + 2047) / 2048;
    const int ntile = (Nn + 63) / 64;

    char* ws = (char*)d_ws;
    size_t off = 0;
    auto alloc = [&](size_t bytes) -> char* {
        char* p = ws + off;
        off = (off + bytes + 255) & ~(size_t)255;
        return p;
    };
    float*        bufA     = (float*)alloc((size_t)Nn * 128 * 4);
    __half*       bufH     = (__half*)alloc((size_t)Nn * 128 * 2);
    float*        as_      = (float*)alloc((size_t)Nn * 4 * 4);
    float*        ad_      = (float*)alloc((size_t)Nn * 4 * 4);
    int*          rowstart = (int*)alloc((size_t)Nn * 4);
    int*          rowdeg   = (int*)alloc((size_t)Nn * 4);
    int*          col      = (int*)alloc((size_t)nbkt * BCAP * 4);
    float*        bn_mul   = (float*)alloc(384 * 4);
    float*        bn_add   = (float*)alloc(384 * 4);
    float*        gsum     = (float*)alloc((size_t)Gg * 128 * 4);
    int*          gcnt     = (int*)alloc((size_t)Gg * 4);
    __bf16*       WtF      = (__bf16*)alloc((size_t)3 * WLSZ * 2);
    unsigned int* bkt      = (unsigned int*)alloc((size_t)nbkt * BCAP * 4);
    int*          bcnt     = (int*)alloc((size_t)nbkt * 4);

    // ---- fused front-end (prep + bucket + gcnt) ----
    hipMemsetAsync(bcnt, 0, (size_t)nbkt * 4, stream);
    k_front<<<nBB + 193, 256, 0, stream>>>(ei, bkt, bcnt, gsum, gcnt, batch,
                                           gamma, beta, bn_mean, bn_var,
                                           bn_mul, bn_add, W, att_src, att_dst,
                                           WtF, Ne, Nn, nbkt, Gg, nBB);

    // ---- merged bscatter + layer-0 GEMM (both depend only on k_front) ----
    k_bsgemm<<<nbkt + ntile, 256, 0, stream>>>(bkt, bcnt, rowstart, rowdeg, col,
                                               x, WtF, bufH, as_, ad_, Nn, nbkt);

    // ---- layer 0 aggregate, then layers 1-2 (layer 3 fuses mean-pool) ----
    k_aggregate<false><<<(Nn + 3) / 4, 256, 0, stream>>>(
        bufH, as_, ad_, rowstart, rowdeg, col, bias, bn_mul, bn_add,
        bufA, batch, gsum, Nn);
    for (int l = 1; l < 3; ++l) {
        k_gemm_mfma<<<ntile, 256, 0, stream>>>(bufA, WtF + l * WLSZ,
                                               bufH, as_, ad_, Nn);
        if (l < 2)
            k_aggregate<false><<<(Nn + 3) / 4, 256, 0, stream>>>(
                bufH, as_, ad_, rowstart, rowdeg, col, bias + l * 128,
                bn_mul + l * 128, bn_add + l * 128, bufA, batch, gsum, Nn);
        else
            k_aggregate<true><<<(Nn + 3) / 4, 256, 0, stream>>>(
                bufH, as_, ad_, rowstart, rowdeg, col, bias + l * 128,
                bn_mul + l * 128, bn_add + l * 128, bufA, batch, gsum, Nn);
    }

    // ---- head ----
    k_head<<<Gg, 64, 0, stream>>>(gsum, gcnt, Wh1, bh1, Wh2, bh2, out);
}